// Round 7
// baseline (53729.675 us; speedup 1.0000x reference)
//
#include <hip/hip_runtime.h>
#include <math.h>

// Problem constants
#define B 64
#define T 512
#define F 256
#define U 1024
#define NBLK 256
#define NTH 512
#define WPAD 68   // zbuf row stride (floats): 68%32=4 -> conflict-free b128 partial stores

typedef unsigned short ushort_t;
typedef __attribute__((ext_vector_type(8))) _Float16 f16x8_t;  // MFMA A/B frag (4 VGPR)
typedef __attribute__((ext_vector_type(4))) float f32x4_t;     // MFMA C/D frag

// ---------------- workspace layout (BYTE offsets) ---------------- (R5 layout)
static const size_t OFF_HT2  = 0;                  // fp32 h2 [U][B]: 262144
static const size_t OFF_STATS= 262144;             // fp32 [2 parity][2][B]: 1024
static const size_t OFF_COND = 263424;             // int[512]: 2048
static const size_t OFF_BAR  = 265472;             // int[1024]: 4096
static const size_t OFF_HB   = 269568;             // f16 h [2][3][B][U]: 786432
static const size_t OFF_XB   = 1056000;            // f16 xbuf [B][F]: 32768
static const size_t OFF_PW0  = 1088768;            // f16 [256 g][40 kt][512]: 10485760
static const size_t OFF_PW1  = 11574528;           // f16 [256][64][512]: 16777216
static const size_t OFF_PW2  = 28351744;           // f16 [256][64][512]: 16777216
static const size_t ZERO_BYTES = OFF_PW0;          // state region zeroed each launch

__device__ __forceinline__ float sigm(float x) {
    return 1.0f / (1.0f + __expf(-x));
}

__device__ __forceinline__ ushort_t f2h(float x) {   // RNE fp32->fp16
    _Float16 h = (_Float16)x;
    union { _Float16 h; ushort_t u; } v; v.h = h;
    return v.u;
}

// Hierarchical grid barrier (round-5 proven version: relaxed polls on ONE gen
// line, hierarchical 8x32 arrival, one acquire fence at exit).
// Round-6 lesson: per-block gen lines + broadcast REGRESSED (extra coherence
// traffic); exit contention was NOT the bottleneck. Keep this simple form.
__device__ __forceinline__ void grid_barrier(int* bar, int epoch) {
    __syncthreads();
    if (threadIdx.x == 0) {
        __builtin_amdgcn_fence(__ATOMIC_RELEASE, "agent");   // wbL2, no inv
        int* sub = bar + (blockIdx.x & 7) * 64;
        int* master = bar + 512;
        int* gen = bar + 576;
        int prev = __hip_atomic_fetch_add(sub, 1, __ATOMIC_RELAXED,
                                          __HIP_MEMORY_SCOPE_AGENT);
        if (prev == 31) {
            int pm = __hip_atomic_fetch_add(master, 1, __ATOMIC_RELAXED,
                                            __HIP_MEMORY_SCOPE_AGENT);
            if (pm == 7) {
                *master = 0;
                #pragma unroll
                for (int i = 0; i < 8; ++i) bar[i * 64] = 0;
                __hip_atomic_store(gen, epoch, __ATOMIC_RELEASE,
                                   __HIP_MEMORY_SCOPE_AGENT);
            }
        }
        int spins = 0;
        while (__hip_atomic_load(gen, __ATOMIC_RELAXED,
                                 __HIP_MEMORY_SCOPE_AGENT) < epoch) {
            __builtin_amdgcn_s_sleep(2);
            if ((++spins & 63) == 0) {  // hang insurance
                (void)__hip_atomic_load(gen, __ATOMIC_ACQUIRE,
                                        __HIP_MEMORY_SCOPE_AGENT);
            }
        }
        __builtin_amdgcn_fence(__ATOMIC_ACQUIRE, "agent");   // the one inv
    }
    __syncthreads();
}

// Prep: decode conditioned_lst (bool-u8 vs int32 sniff), init f16 xbuf.
__global__ void prep_kernel(const unsigned char* __restrict__ condraw,
                            const float* __restrict__ input,
                            unsigned char* __restrict__ wsb) {
    __shared__ int s_not_int32;
    const int tid = threadIdx.x;
    if (tid == 0) s_not_int32 = 0;
    __syncthreads();
    if (tid < 512 && (tid & 3) != 0) {
        if (condraw[tid] != 0) s_not_int32 = 1;
    }
    __syncthreads();
    const int is32 = (s_not_int32 == 0);
    int* condw = (int*)(wsb + OFF_COND);
    if (tid < 512) {
        int cv = is32 ? ((const int*)condraw)[tid] : (int)condraw[tid];
        condw[tid] = (cv != 0) ? 1 : 0;
    }
    ushort_t* xb = (ushort_t*)(wsb + OFF_XB);
    for (int i = tid; i < B * F; i += blockDim.x) {
        const int b = i >> 8, f = i & 255;
        xb[i] = f2h(input[(size_t)b * (T * F) + f]);
    }
}

// Repack fp32 weights -> fp16 in MFMA B-fragment order:
// PW_l[((g*KT + kt)*64 + L)*8 + j] = W_l[k][col], k = kt*32 + (L>>4)*8 + j,
// n = L&15, col = (n>>2)*1024 + g*4 + (n&3)
__global__ void repack_kernel(const float* __restrict__ W0,
                              const float* __restrict__ W1,
                              const float* __restrict__ W2,
                              unsigned char* __restrict__ wsb) {
    ushort_t* P0 = (ushort_t*)(wsb + OFF_PW0);
    ushort_t* P1 = (ushort_t*)(wsb + OFF_PW1);
    ushort_t* P2 = (ushort_t*)(wsb + OFF_PW2);
    const size_t stride = (size_t)gridDim.x * blockDim.x;
    const size_t tid = (size_t)blockIdx.x * blockDim.x + threadIdx.x;
    const size_t N0 = (size_t)256 * 40 * 512;
    const size_t N12 = (size_t)256 * 64 * 512;
    for (size_t i = tid; i < N0; i += stride) {
        const int g = (int)(i / 20480);
        const int r = (int)(i % 20480);
        const int kt = r >> 9, s = r & 511, L = s >> 3, j = s & 7;
        const int k = kt * 32 + ((L >> 4) << 3) + j;
        const int n = L & 15;
        const int col = ((n >> 2) << 10) + (g << 2) + (n & 3);
        P0[i] = f2h(W0[(size_t)k * 4096 + col]);
    }
    for (size_t i = tid; i < N12; i += stride) {
        const int g = (int)(i / 32768);
        const int r = (int)(i % 32768);
        const int kt = r >> 9, s = r & 511, L = s >> 3, j = s & 7;
        const int k = kt * 32 + ((L >> 4) << 3) + j;
        const int n = L & 15;
        const int col = ((n >> 2) << 10) + (g << 2) + (n & 3);
        const size_t src = (size_t)k * 4096 + col;
        P1[i] = f2h(W1[src]);
        P2[i] = f2h(W2[src]);
    }
}

__global__ void __launch_bounds__(NTH, 2)
lstm_persistent(const float* __restrict__ input,
                const float* __restrict__ b0, const float* __restrict__ b1,
                const float* __restrict__ b2,
                const float* __restrict__ Wd, const float* __restrict__ bd,
                const float* __restrict__ gamma, const float* __restrict__ beta,
                float* __restrict__ out, unsigned char* __restrict__ wsb) {
    const int g = blockIdx.x;
    const int tid = threadIdx.x;
    const int lane = tid & 63;
    const int wv = __builtin_amdgcn_readfirstlane(tid >> 6);  // 0..7
    const int ln15 = lane & 15;
    const int quad = lane >> 4;
    const int kofs = quad << 3;

    float* hT2 = (float*)(wsb + OFF_HT2);          // fp32 [U][B]
    float* stats = (float*)(wsb + OFF_STATS);
    const int* cond = (const int*)(wsb + OFF_COND);
    int* bar = (int*)(wsb + OFF_BAR);
    ushort_t* hb = (ushort_t*)(wsb + OFF_HB);      // f16 [2][3][B][U]
    ushort_t* xb = (ushort_t*)(wsb + OFF_XB);      // f16 [B][F]

    // ---- inv-proof weight residency (round-7 change) ----
    // L2 is invalidated by every barrier's acquire fence -> weights must NOT
    // live in L2. L1/L2-layer B-frags go to REGISTERS (64 VGPRs), L0 weights
    // and Wd go to LDS. Per-step global traffic becomes state-only (~1.5 MB).
    __shared__ f16x8_t lds_pw0[40 * 64];     // 40 KB: L0 B-frags [kt][lane]
    __shared__ f32x4_t lds_wd4[1024];        // 16 KB: Wd[k][f0..f0+3] (g<64)
    __shared__ float zbuf[128 * WPAD];       // 34.8 KB cross-wave reduction

    const int u0 = g << 2;   // block's unit quad
    const int f0 = g << 2;   // dense cols (g < 64)

    // preload L1/L2 B-fragments into registers (persistent across t-loop)
    f16x8_t Bw1[8], Bw2[8];
    {
        const ushort_t* p1 = (const ushort_t*)(wsb + OFF_PW1) +
                             ((size_t)g * 64 + wv * 8) * 512 + lane * 8;
        const ushort_t* p2 = (const ushort_t*)(wsb + OFF_PW2) +
                             ((size_t)g * 64 + wv * 8) * 512 + lane * 8;
        #pragma unroll
        for (int i = 0; i < 8; ++i) Bw1[i] = *(const f16x8_t*)(p1 + (size_t)i * 512);
        #pragma unroll
        for (int i = 0; i < 8; ++i) Bw2[i] = *(const f16x8_t*)(p2 + (size_t)i * 512);
    }
    // stage L0 weights into LDS (linear 40 KB copy)
    {
        const f16x8_t* src = (const f16x8_t*)((const ushort_t*)(wsb + OFF_PW0) +
                                              (size_t)g * 40 * 512);
        for (int i = tid; i < 40 * 64; i += NTH) lds_pw0[i] = src[i];
    }
    // stage Wd columns into LDS (dense blocks only)
    if (g < 64) {
        for (int k = tid; k < 1024; k += NTH)
            lds_wd4[k] = *(const f32x4_t*)(Wd + (size_t)k * F + f0);
    }
    __syncthreads();

    const int eb = tid & 63;
    const int eu = (tid >> 6) & 3;
    float creg[3] = {0.f, 0.f, 0.f};   // fp32 cell state (valid for tid<256)

    int epoch = 0;
    for (int t = 0; t < T; ++t) {
        const int p = t & 1;
        const int pn = p ^ 1;

        // ---------------- LSTM layers: MFMA z^(l) = X W ----------------
        for (int l = 0; l < 3; ++l) {
            const ushort_t* xsrc = (l == 0) ? xb
                                 : (hb + ((size_t)(pn * 3 + (l - 1))) * B * U);
            const ushort_t* hsrc = hb + ((size_t)(p * 3 + l)) * B * U;

            f32x4_t acc[4];
            #pragma unroll
            for (int mt = 0; mt < 4; ++mt) acc[mt] = (f32x4_t){0.f, 0.f, 0.f, 0.f};

            if (l == 0) {
                // 5 ktiles/wave; B from LDS; A from xb (k<256) or h (k>=256)
                const int kt0 = wv * 5;
                #pragma unroll
                for (int base = 0; base < 5; base += 4) {
                    const int CH = (5 - base) < 4 ? (5 - base) : 4;
                    f16x8_t Bb[4];
                    f16x8_t Ab[4][4];
                    #pragma unroll
                    for (int c = 0; c < 4; ++c) {
                        if (c < CH) {
                            const int kt = kt0 + base + c;
                            Bb[c] = lds_pw0[kt * 64 + lane];
                            const int kg = kt * 32;
                            const ushort_t* ab;
                            int rs;
                            if (kg < F) { ab = xsrc + kg; rs = F; }
                            else        { ab = hsrc + (kg - F); rs = U; }
                            const ushort_t* lp = ab + (size_t)ln15 * rs + kofs;
                            #pragma unroll
                            for (int mt = 0; mt < 4; ++mt)
                                Ab[c][mt] = *(const f16x8_t*)(lp + (size_t)mt * 16 * rs);
                        }
                    }
                    #pragma unroll
                    for (int c = 0; c < 4; ++c) {
                        if (c < CH) {
                            #pragma unroll
                            for (int mt = 0; mt < 4; ++mt)
                                acc[mt] = __builtin_amdgcn_mfma_f32_16x16x32_f16(
                                    Ab[c][mt], Bb[c], acc[mt], 0, 0, 0);
                        }
                    }
                }
            } else {
                // 8 ktiles/wave; B from registers; A from x-part or h-part
                const f16x8_t* Bw = (l == 1) ? Bw1 : Bw2;
                const int kt0 = wv * 8;
                #pragma unroll
                for (int base = 0; base < 8; base += 4) {
                    f16x8_t Ab[4][4];
                    #pragma unroll
                    for (int c = 0; c < 4; ++c) {
                        const int kt = kt0 + base + c;
                        const int kg = kt * 32;
                        const ushort_t* ab = (kg < U) ? (xsrc + kg)
                                                      : (hsrc + (kg - U));
                        const ushort_t* lp = ab + (size_t)ln15 * U + kofs;
                        #pragma unroll
                        for (int mt = 0; mt < 4; ++mt)
                            Ab[c][mt] = *(const f16x8_t*)(lp + (size_t)mt * 16 * U);
                    }
                    #pragma unroll
                    for (int c = 0; c < 4; ++c) {
                        #pragma unroll
                        for (int mt = 0; mt < 4; ++mt)
                            acc[mt] = __builtin_amdgcn_mfma_f32_16x16x32_f16(
                                Ab[c][mt], Bw[base + c], acc[mt], 0, 0, 0);
                    }
                }
            }

            __syncthreads();
            {
                float* zrow = zbuf + (size_t)(wv * 16 + ln15) * WPAD;
                #pragma unroll
                for (int mt = 0; mt < 4; ++mt)
                    *(f32x4_t*)(zrow + mt * 16 + (quad << 2)) = acc[mt];
            }
            __syncthreads();

            if (tid < 256) {   // gate epilogue: (b=eb, unit u0+eu)
                const float* bvec = (l == 0) ? b0 : ((l == 1) ? b1 : b2);
                float z[4];
                #pragma unroll
                for (int q = 0; q < 4; ++q) {
                    float s = bvec[(q << 10) + u0 + eu];
                    #pragma unroll
                    for (int w = 0; w < 8; ++w)
                        s += zbuf[(size_t)(w * 16 + q * 4 + eu) * WPAD + eb];
                    z[q] = s;
                }
                const float ig = sigm(z[0]);
                const float gg = tanhf(z[1]);
                const float fg = sigm(z[2] + 1.0f);   // forget_bias = 1.0
                const float og = sigm(z[3]);
                const float cn = creg[l] * fg + ig * gg;
                const float hn = og * tanhf(cn);
                creg[l] = cn;
                hb[((size_t)(pn * 3 + l)) * B * U + (size_t)eb * U + u0 + eu] = f2h(hn);
                if (l == 2) hT2[(size_t)(u0 + eu) * B + eb] = hn;
            }
            grid_barrier(bar, ++epoch);
        }

        // ---------------- dense projection + LN stats ----------------
        float yv[4] = {0.f, 0.f, 0.f, 0.f};
        if (g < 64) {
            float accd[4] = {0.f, 0.f, 0.f, 0.f};
            const int k0 = wv << 7;   // U/8 = 128 per wave
            #pragma unroll 8
            for (int k = k0; k < k0 + 128; ++k) {
                const float xv = hT2[(size_t)k * B + lane];
                const f32x4_t w4 = lds_wd4[k];
                accd[0] = fmaf(w4.x, xv, accd[0]);
                accd[1] = fmaf(w4.y, xv, accd[1]);
                accd[2] = fmaf(w4.z, xv, accd[2]);
                accd[3] = fmaf(w4.w, xv, accd[3]);
            }
            __syncthreads();
            #pragma unroll
            for (int jj = 0; jj < 4; ++jj)
                zbuf[(size_t)(wv * 16 + jj) * WPAD + lane] = accd[jj];
            __syncthreads();
            if (wv == 0) {
                const float4 bd4 = *(const float4*)(bd + f0);
                float s = 0.f, ss = 0.f;
                #pragma unroll
                for (int jj = 0; jj < 4; ++jj) {
                    float y = 0.f;
                    #pragma unroll
                    for (int w = 0; w < 8; ++w)
                        y += zbuf[(size_t)(w * 16 + jj) * WPAD + lane];
                    y += (jj == 0) ? bd4.x : (jj == 1) ? bd4.y : (jj == 2) ? bd4.z : bd4.w;
                    yv[jj] = y;
                    s += y;
                    ss += y * y;
                }
                float* st = stats + (size_t)(t & 1) * 2 * B;
                atomicAdd(&st[lane], s);
                atomicAdd(&st[B + lane], ss);
            }
            __syncthreads();
        }
        grid_barrier(bar, ++epoch);

        // ---------------- LN + ReLU emit ----------------
        if (g < 64 && wv == 0) {
            const float* st = stats + (size_t)(t & 1) * 2 * B;
            const float mu = st[lane] * (1.0f / F);
            const float var = st[B + lane] * (1.0f / F) - mu * mu;
            const float rs = rsqrtf(var + 1e-12f);
            const float4 gm = *(const float4*)(gamma + f0);
            const float4 bt = *(const float4*)(beta + f0);
            float em[4];
            em[0] = fmaxf((yv[0] - mu) * rs * gm.x + bt.x, 0.0f);
            em[1] = fmaxf((yv[1] - mu) * rs * gm.y + bt.y, 0.0f);
            em[2] = fmaxf((yv[2] - mu) * rs * gm.z + bt.z, 0.0f);
            em[3] = fmaxf((yv[3] - mu) * rs * gm.w + bt.w, 0.0f);
            *(float4*)(out + (size_t)lane * (T * F) + (size_t)t * F + f0) =
                make_float4(em[0], em[1], em[2], em[3]);
            if (t + 1 < T) {
                float xn[4];
                if (cond[t + 1] != 0) {
                    const float4 iv = *(const float4*)(input + (size_t)lane * (T * F) +
                                                       (size_t)(t + 1) * F + f0);
                    xn[0] = iv.x; xn[1] = iv.y; xn[2] = iv.z; xn[3] = iv.w;
                } else {
                    xn[0] = em[0]; xn[1] = em[1]; xn[2] = em[2]; xn[3] = em[3];
                }
                #pragma unroll
                for (int jj = 0; jj < 4; ++jj)
                    xb[(size_t)lane * F + f0 + jj] = f2h(xn[jj]);
            }
        }
        if (g == 0 && wv == 1) {   // zero other-parity stats for step t+1
            float* st2 = stats + (size_t)((t + 1) & 1) * 2 * B;
            st2[lane] = 0.0f;
            st2[B + lane] = 0.0f;
        }
        grid_barrier(bar, ++epoch);
    }
}

extern "C" void kernel_launch(void* const* d_in, const int* in_sizes, int n_in,
                              void* d_out, int out_size, void* d_ws, size_t ws_size,
                              hipStream_t stream) {
    const float* input = (const float*)d_in[0];
    const unsigned char* condraw = (const unsigned char*)d_in[1];
    const float* W0 = (const float*)d_in[2];
    const float* b0 = (const float*)d_in[3];
    const float* W1 = (const float*)d_in[4];
    const float* b1 = (const float*)d_in[5];
    const float* W2 = (const float*)d_in[6];
    const float* b2 = (const float*)d_in[7];
    const float* Wd = (const float*)d_in[8];
    const float* bd = (const float*)d_in[9];
    const float* gamma = (const float*)d_in[10];
    const float* beta = (const float*)d_in[11];
    float* out = (float*)d_out;
    unsigned char* wsb = (unsigned char*)d_ws;

    hipMemsetAsync(d_ws, 0, ZERO_BYTES, stream);
    prep_kernel<<<1, 512, 0, stream>>>(condraw, input, wsb);
    repack_kernel<<<2048, 256, 0, stream>>>(W0, W1, W2, wsb);
    lstm_persistent<<<NBLK, NTH, 0, stream>>>(input, b0, b1, b2, Wd, bd,
                                              gamma, beta, out, wsb);
}

// Round 8
// 42614.908 us; speedup vs baseline: 1.2608x; 1.2608x over previous
//
#include <hip/hip_runtime.h>
#include <math.h>

// Problem constants
#define B 64
#define T 512
#define F 256
#define U 1024
#define NBLK 256
#define NTH 512
#define WPAD 68   // zbuf row stride (floats): 68%32=4 -> conflict-free b128 partial stores

typedef unsigned short ushort_t;
typedef __attribute__((ext_vector_type(8))) _Float16 f16x8_t;  // MFMA A/B frag (4 VGPR)
typedef __attribute__((ext_vector_type(4))) float f32x4_t;     // MFMA C/D frag

// ---------------- workspace layout (BYTE offsets) ----------------
static const size_t OFF_HT2  = 0;                  // fp32 h2 [U][B]: 262144
static const size_t OFF_STATS= 262144;             // fp32 [2 parity][2][B]: 1024
static const size_t OFF_COND = 263424;             // int[512]: 2048
static const size_t OFF_BAR  = 265472;             // int[1024]: 4096
static const size_t OFF_HB   = 269568;             // f16 h [2][3][B][U]: 786432
static const size_t OFF_XB   = 1056000;            // f16 xbuf [B][F]: 32768
static const size_t OFF_PW0  = 1088768;            // f16 [256 g][40 kt][512]: 10485760
static const size_t OFF_PW1  = 11574528;           // f16 [256][64][512]: 16777216
static const size_t OFF_PW2  = 28351744;           // f16 [256][64][512]: 16777216
static const size_t ZERO_BYTES = OFF_PW0;          // state region zeroed each launch
// bar int-offsets (one 64B line each): sub[i]=i*16 (i<8); master=128;
// relay[i]=144+i*16 (i<8); minibar=272.

__device__ __forceinline__ float sigm(float x) {
    return 1.0f / (1.0f + __expf(-x));
}

__device__ __forceinline__ ushort_t f2h(float x) {   // RNE fp32->fp16
    _Float16 h = (_Float16)x;
    union { _Float16 h; ushort_t u; } v; v.h = h;
    return v.u;
}

// ---- write-through (device-coherent) stores: data lands at the coherence
// point, so consumers need NO release fence and NO per-phase acquire inv.
__device__ __forceinline__ void store_uc_u16(ushort_t* p, ushort_t v) {
    asm volatile("global_store_short %0, %1, off sc0 sc1"
                 :: "v"(p), "v"((unsigned)v) : "memory");
}
__device__ __forceinline__ void store_uc_f32(float* p, float v) {
    asm volatile("global_store_dword %0, %1, off sc0 sc1"
                 :: "v"(p), "v"(v) : "memory");
}
__device__ __forceinline__ void store_uc_b64(void* p, unsigned long long v) {
    asm volatile("global_store_dwordx2 %0, %1, off sc0 sc1"
                 :: "v"(p), "v"(v) : "memory");
}
__device__ __forceinline__ void drain_vmem() {
    asm volatile("s_waitcnt vmcnt(0)" ::: "memory");
}

// Fence-free phase sync (round-8). Monotonic epoch; hierarchical arrival
// (8 lines x 32); releaser resets counters, drains, then publishes epoch to
// 8 relay lines (32 pollers/line, not 256/line). Relaxed polls; NO acquire
// fence at exit — freshness is provided by the once-per-step inv at loop top
// (producers store write-through). Insurance acquire-load every 64 spins.
__device__ __forceinline__ void phase_sync(int* bar, int epoch, int g) {
    drain_vmem();        // each wave drains its own (incl. asm) stores
    __syncthreads();
    if (threadIdx.x == 0) {
        int prev = __hip_atomic_fetch_add(bar + (g & 7) * 16, 1,
                                          __ATOMIC_RELAXED, __HIP_MEMORY_SCOPE_AGENT);
        if (prev == 31) {
            int pm = __hip_atomic_fetch_add(bar + 128, 1,
                                            __ATOMIC_RELAXED, __HIP_MEMORY_SCOPE_AGENT);
            if (pm == 7) {
                #pragma unroll
                for (int i = 0; i < 8; ++i)
                    __hip_atomic_store(bar + i * 16, 0, __ATOMIC_RELAXED,
                                       __HIP_MEMORY_SCOPE_AGENT);
                __hip_atomic_store(bar + 128, 0, __ATOMIC_RELAXED,
                                   __HIP_MEMORY_SCOPE_AGENT);
                drain_vmem();   // resets land before epoch publication
                #pragma unroll
                for (int i = 0; i < 8; ++i)
                    __hip_atomic_store(bar + 144 + i * 16, epoch, __ATOMIC_RELAXED,
                                       __HIP_MEMORY_SCOPE_AGENT);
            }
        }
        int* myrelay = bar + 144 + (g & 7) * 16;
        int spins = 0;
        while (__hip_atomic_load(myrelay, __ATOMIC_RELAXED,
                                 __HIP_MEMORY_SCOPE_AGENT) < epoch) {
            __builtin_amdgcn_s_sleep(4);
            if ((++spins & 63) == 0)
                (void)__hip_atomic_load(myrelay, __ATOMIC_ACQUIRE,
                                        __HIP_MEMORY_SCOPE_AGENT);
        }
    }
    __syncthreads();
}

// Prep: decode conditioned_lst (bool-u8 vs int32 sniff), init f16 xbuf.
__global__ void prep_kernel(const unsigned char* __restrict__ condraw,
                            const float* __restrict__ input,
                            unsigned char* __restrict__ wsb) {
    __shared__ int s_not_int32;
    const int tid = threadIdx.x;
    if (tid == 0) s_not_int32 = 0;
    __syncthreads();
    if (tid < 512 && (tid & 3) != 0) {
        if (condraw[tid] != 0) s_not_int32 = 1;
    }
    __syncthreads();
    const int is32 = (s_not_int32 == 0);
    int* condw = (int*)(wsb + OFF_COND);
    if (tid < 512) {
        int cv = is32 ? ((const int*)condraw)[tid] : (int)condraw[tid];
        condw[tid] = (cv != 0) ? 1 : 0;
    }
    ushort_t* xb = (ushort_t*)(wsb + OFF_XB);
    for (int i = tid; i < B * F; i += blockDim.x) {
        const int b = i >> 8, f = i & 255;
        xb[i] = f2h(input[(size_t)b * (T * F) + f]);
    }
}

// Repack fp32 weights -> fp16 in MFMA B-fragment order:
// PW_l[((g*KT + kt)*64 + L)*8 + j] = W_l[k][col], k = kt*32 + (L>>4)*8 + j,
// n = L&15, col = (n>>2)*1024 + g*4 + (n&3)
__global__ void repack_kernel(const float* __restrict__ W0,
                              const float* __restrict__ W1,
                              const float* __restrict__ W2,
                              unsigned char* __restrict__ wsb) {
    ushort_t* P0 = (ushort_t*)(wsb + OFF_PW0);
    ushort_t* P1 = (ushort_t*)(wsb + OFF_PW1);
    ushort_t* P2 = (ushort_t*)(wsb + OFF_PW2);
    const size_t stride = (size_t)gridDim.x * blockDim.x;
    const size_t tid = (size_t)blockIdx.x * blockDim.x + threadIdx.x;
    const size_t N0 = (size_t)256 * 40 * 512;
    const size_t N12 = (size_t)256 * 64 * 512;
    for (size_t i = tid; i < N0; i += stride) {
        const int g = (int)(i / 20480);
        const int r = (int)(i % 20480);
        const int kt = r >> 9, s = r & 511, L = s >> 3, j = s & 7;
        const int k = kt * 32 + ((L >> 4) << 3) + j;
        const int n = L & 15;
        const int col = ((n >> 2) << 10) + (g << 2) + (n & 3);
        P0[i] = f2h(W0[(size_t)k * 4096 + col]);
    }
    for (size_t i = tid; i < N12; i += stride) {
        const int g = (int)(i / 32768);
        const int r = (int)(i % 32768);
        const int kt = r >> 9, s = r & 511, L = s >> 3, j = s & 7;
        const int k = kt * 32 + ((L >> 4) << 3) + j;
        const int n = L & 15;
        const int col = ((n >> 2) << 10) + (g << 2) + (n & 3);
        const size_t src = (size_t)k * 4096 + col;
        P1[i] = f2h(W1[src]);
        P2[i] = f2h(W2[src]);
    }
}

__global__ void __launch_bounds__(NTH, 2)
lstm_persistent(const float* __restrict__ input,
                const float* __restrict__ b0, const float* __restrict__ b1,
                const float* __restrict__ b2,
                const float* __restrict__ Wd, const float* __restrict__ bd,
                const float* __restrict__ gamma, const float* __restrict__ beta,
                float* __restrict__ out, unsigned char* __restrict__ wsb) {
    const int g = blockIdx.x;
    const int tid = threadIdx.x;
    const int lane = tid & 63;
    const int wv = __builtin_amdgcn_readfirstlane(tid >> 6);  // 0..7
    const int ln15 = lane & 15;
    const int quad = lane >> 4;
    const int kofs = quad << 3;

    float* hT2 = (float*)(wsb + OFF_HT2);          // fp32 [U][B]
    float* stats = (float*)(wsb + OFF_STATS);
    int* bar = (int*)(wsb + OFF_BAR);
    ushort_t* hb = (ushort_t*)(wsb + OFF_HB);      // f16 [2][3][B][U]
    ushort_t* xb = (ushort_t*)(wsb + OFF_XB);      // f16 [B][F]

    // inv-proof residency (round-7, kept): weights in regs + LDS; cond in LDS.
    __shared__ f16x8_t lds_pw0[40 * 64];     // 40 KB: L0 B-frags
    __shared__ f32x4_t lds_wd4[1024];        // 16 KB: Wd cols (g<64)
    __shared__ float zbuf[128 * WPAD];       // 34.8 KB
    __shared__ int lds_cond[512];            // 2 KB

    const int u0 = g << 2;
    const int f0 = g << 2;

    f16x8_t Bw1[8], Bw2[8];
    {
        const ushort_t* p1 = (const ushort_t*)(wsb + OFF_PW1) +
                             ((size_t)g * 64 + wv * 8) * 512 + lane * 8;
        const ushort_t* p2 = (const ushort_t*)(wsb + OFF_PW2) +
                             ((size_t)g * 64 + wv * 8) * 512 + lane * 8;
        #pragma unroll
        for (int i = 0; i < 8; ++i) Bw1[i] = *(const f16x8_t*)(p1 + (size_t)i * 512);
        #pragma unroll
        for (int i = 0; i < 8; ++i) Bw2[i] = *(const f16x8_t*)(p2 + (size_t)i * 512);
    }
    {
        const f16x8_t* src = (const f16x8_t*)((const ushort_t*)(wsb + OFF_PW0) +
                                              (size_t)g * 40 * 512);
        for (int i = tid; i < 40 * 64; i += NTH) lds_pw0[i] = src[i];
    }
    if (g < 64) {
        for (int k = tid; k < 1024; k += NTH)
            lds_wd4[k] = *(const f32x4_t*)(Wd + (size_t)k * F + f0);
    }
    for (int i = tid; i < 512; i += NTH) lds_cond[i] = ((const int*)(wsb + OFF_COND))[i];

    const int eb = tid & 63;
    const int eu = (tid >> 6) & 3;
    float creg[3] = {0.f, 0.f, 0.f};

    // loop-invariant hoists (survive the per-step inv in registers)
    float bias[3][4];
    if (tid < 256) {
        #pragma unroll
        for (int q = 0; q < 4; ++q) {
            bias[0][q] = b0[(q << 10) + u0 + eu];
            bias[1][q] = b1[(q << 10) + u0 + eu];
            bias[2][q] = b2[(q << 10) + u0 + eu];
        }
    }
    float4 gm4 = {0,0,0,0}, bt4 = {0,0,0,0}, bd4 = {0,0,0,0};
    if (g < 64 && wv == 0) {
        gm4 = *(const float4*)(gamma + f0);
        bt4 = *(const float4*)(beta + f0);
        bd4 = *(const float4*)(bd + f0);
    }
    __syncthreads();

    int epoch = 0;
    for (int t = 0; t < T; ++t) {
        const int p = t & 1;
        const int pn = p ^ 1;

        // THE one inv per step: wipes L1/L2 so this step's cached state reads
        // are fresh. Weights (regs/LDS) unaffected.
        __builtin_amdgcn_fence(__ATOMIC_ACQUIRE, "agent");

        // ---------------- LSTM layers: MFMA z^(l) = X W ----------------
        for (int l = 0; l < 3; ++l) {
            const ushort_t* xsrc = (l == 0) ? xb
                                 : (hb + ((size_t)(pn * 3 + (l - 1))) * B * U);
            const ushort_t* hsrc = hb + ((size_t)(p * 3 + l)) * B * U;

            f32x4_t acc[4];
            #pragma unroll
            for (int mt = 0; mt < 4; ++mt) acc[mt] = (f32x4_t){0.f, 0.f, 0.f, 0.f};

            if (l == 0) {
                const int kt0 = wv * 5;
                #pragma unroll
                for (int base = 0; base < 5; base += 4) {
                    const int CH = (5 - base) < 4 ? (5 - base) : 4;
                    f16x8_t Bb[4];
                    f16x8_t Ab[4][4];
                    #pragma unroll
                    for (int c = 0; c < 4; ++c) {
                        if (c < CH) {
                            const int kt = kt0 + base + c;
                            Bb[c] = lds_pw0[kt * 64 + lane];
                            const int kg = kt * 32;
                            const ushort_t* ab;
                            int rs;
                            if (kg < F) { ab = xsrc + kg; rs = F; }
                            else        { ab = hsrc + (kg - F); rs = U; }
                            const ushort_t* lp = ab + (size_t)ln15 * rs + kofs;
                            #pragma unroll
                            for (int mt = 0; mt < 4; ++mt)
                                Ab[c][mt] = *(const f16x8_t*)(lp + (size_t)mt * 16 * rs);
                        }
                    }
                    #pragma unroll
                    for (int c = 0; c < 4; ++c) {
                        if (c < CH) {
                            #pragma unroll
                            for (int mt = 0; mt < 4; ++mt)
                                acc[mt] = __builtin_amdgcn_mfma_f32_16x16x32_f16(
                                    Ab[c][mt], Bb[c], acc[mt], 0, 0, 0);
                        }
                    }
                }
            } else {
                const f16x8_t* Bw = (l == 1) ? Bw1 : Bw2;
                const int kt0 = wv * 8;
                #pragma unroll
                for (int base = 0; base < 8; base += 4) {
                    f16x8_t Ab[4][4];
                    #pragma unroll
                    for (int c = 0; c < 4; ++c) {
                        const int kt = kt0 + base + c;
                        const int kg = kt * 32;
                        const ushort_t* ab = (kg < U) ? (xsrc + kg)
                                                      : (hsrc + (kg - U));
                        const ushort_t* lp = ab + (size_t)ln15 * U + kofs;
                        #pragma unroll
                        for (int mt = 0; mt < 4; ++mt)
                            Ab[c][mt] = *(const f16x8_t*)(lp + (size_t)mt * 16 * U);
                    }
                    #pragma unroll
                    for (int c = 0; c < 4; ++c) {
                        #pragma unroll
                        for (int mt = 0; mt < 4; ++mt)
                            acc[mt] = __builtin_amdgcn_mfma_f32_16x16x32_f16(
                                Ab[c][mt], Bw[base + c], acc[mt], 0, 0, 0);
                    }
                }
            }

            __syncthreads();
            {
                float* zrow = zbuf + (size_t)(wv * 16 + ln15) * WPAD;
                #pragma unroll
                for (int mt = 0; mt < 4; ++mt)
                    *(f32x4_t*)(zrow + mt * 16 + (quad << 2)) = acc[mt];
            }
            __syncthreads();

            if (tid < 256) {   // gate epilogue: (b=eb, unit u0+eu)
                float z[4];
                #pragma unroll
                for (int q = 0; q < 4; ++q) {
                    float s = bias[l][q];
                    #pragma unroll
                    for (int w = 0; w < 8; ++w)
                        s += zbuf[(size_t)(w * 16 + q * 4 + eu) * WPAD + eb];
                    z[q] = s;
                }
                const float ig = sigm(z[0]);
                const float gg = tanhf(z[1]);
                const float fg = sigm(z[2] + 1.0f);   // forget_bias = 1.0
                const float og = sigm(z[3]);
                const float cn = creg[l] * fg + ig * gg;
                const float hn = og * tanhf(cn);
                creg[l] = cn;
                store_uc_u16(hb + ((size_t)(pn * 3 + l)) * B * U +
                             (size_t)eb * U + u0 + eu, f2h(hn));
                if (l == 2) store_uc_f32(hT2 + (size_t)(u0 + eu) * B + eb, hn);
            }
            phase_sync(bar, ++epoch, g);
        }

        // ------- dense + LN stats + mini-sync + LN + emit (ONE phase) -------
        if (g < 64) {
            float accd[4] = {0.f, 0.f, 0.f, 0.f};
            const int k0 = wv << 7;   // U/8 = 128 per wave
            #pragma unroll 8
            for (int k = k0; k < k0 + 128; ++k) {
                const float xv = hT2[(size_t)k * B + lane];
                const f32x4_t w4 = lds_wd4[k];
                accd[0] = fmaf(w4.x, xv, accd[0]);
                accd[1] = fmaf(w4.y, xv, accd[1]);
                accd[2] = fmaf(w4.z, xv, accd[2]);
                accd[3] = fmaf(w4.w, xv, accd[3]);
            }
            __syncthreads();
            #pragma unroll
            for (int jj = 0; jj < 4; ++jj)
                zbuf[(size_t)(wv * 16 + jj) * WPAD + lane] = accd[jj];
            __syncthreads();
            if (wv == 0) {
                float yv[4];
                float s = 0.f, ss = 0.f;
                #pragma unroll
                for (int jj = 0; jj < 4; ++jj) {
                    float y = 0.f;
                    #pragma unroll
                    for (int w = 0; w < 8; ++w)
                        y += zbuf[(size_t)(w * 16 + jj) * WPAD + lane];
                    y += (jj == 0) ? bd4.x : (jj == 1) ? bd4.y : (jj == 2) ? bd4.z : bd4.w;
                    yv[jj] = y;
                    s += y;
                    ss += y * y;
                }
                float* st = stats + (size_t)(t & 1) * 2 * B;
                atomicAdd(&st[lane], s);
                atomicAdd(&st[B + lane], ss);
                // mini-sync among 64 dense blocks (monotonic, fence-free)
                if (lane == 0) {
                    drain_vmem();   // wave-wide: stats adds complete
                    __hip_atomic_fetch_add(bar + 272, 1, __ATOMIC_RELAXED,
                                           __HIP_MEMORY_SCOPE_AGENT);
                    const int target = (t + 1) * 64;
                    int spins = 0;
                    while (__hip_atomic_load(bar + 272, __ATOMIC_RELAXED,
                                             __HIP_MEMORY_SCOPE_AGENT) < target) {
                        __builtin_amdgcn_s_sleep(4);
                        if ((++spins & 63) == 0)
                            (void)__hip_atomic_load(bar + 272, __ATOMIC_ACQUIRE,
                                                    __HIP_MEMORY_SCOPE_AGENT);
                    }
                }
                // plain loads: stats lines not cached on this XCD since the
                // step-start inv (atomics bypass), so this fetch is fresh
                const float mu = st[lane] * (1.0f / F);
                const float var = st[B + lane] * (1.0f / F) - mu * mu;
                const float rs = rsqrtf(var + 1e-12f);
                float em[4];
                em[0] = fmaxf((yv[0] - mu) * rs * gm4.x + bt4.x, 0.0f);
                em[1] = fmaxf((yv[1] - mu) * rs * gm4.y + bt4.y, 0.0f);
                em[2] = fmaxf((yv[2] - mu) * rs * gm4.z + bt4.z, 0.0f);
                em[3] = fmaxf((yv[3] - mu) * rs * gm4.w + bt4.w, 0.0f);
                *(float4*)(out + (size_t)lane * (T * F) + (size_t)t * F + f0) =
                    make_float4(em[0], em[1], em[2], em[3]);
                if (t + 1 < T) {
                    float xn[4];
                    if (lds_cond[t + 1] != 0) {
                        const float4 iv = *(const float4*)(input + (size_t)lane * (T * F) +
                                                           (size_t)(t + 1) * F + f0);
                        xn[0] = iv.x; xn[1] = iv.y; xn[2] = iv.z; xn[3] = iv.w;
                    } else {
                        xn[0] = em[0]; xn[1] = em[1]; xn[2] = em[2]; xn[3] = em[3];
                    }
                    unsigned long long pk =
                        (unsigned long long)f2h(xn[0]) |
                        ((unsigned long long)f2h(xn[1]) << 16) |
                        ((unsigned long long)f2h(xn[2]) << 32) |
                        ((unsigned long long)f2h(xn[3]) << 48);
                    store_uc_b64(xb + (size_t)lane * F + f0, pk);
                }
            }
        } else if (g == 64 && wv == 0) {
            // zero other-parity stats for step t+1 (write-through)
            float* st2 = stats + (size_t)((t + 1) & 1) * 2 * B;
            store_uc_f32(&st2[lane], 0.0f);
            store_uc_f32(&st2[B + lane], 0.0f);
        }
        phase_sync(bar, ++epoch, g);
    }
}

extern "C" void kernel_launch(void* const* d_in, const int* in_sizes, int n_in,
                              void* d_out, int out_size, void* d_ws, size_t ws_size,
                              hipStream_t stream) {
    const float* input = (const float*)d_in[0];
    const unsigned char* condraw = (const unsigned char*)d_in[1];
    const float* W0 = (const float*)d_in[2];
    const float* b0 = (const float*)d_in[3];
    const float* W1 = (const float*)d_in[4];
    const float* b1 = (const float*)d_in[5];
    const float* W2 = (const float*)d_in[6];
    const float* b2 = (const float*)d_in[7];
    const float* Wd = (const float*)d_in[8];
    const float* bd = (const float*)d_in[9];
    const float* gamma = (const float*)d_in[10];
    const float* beta = (const float*)d_in[11];
    float* out = (float*)d_out;
    unsigned char* wsb = (unsigned char*)d_ws;

    hipMemsetAsync(d_ws, 0, ZERO_BYTES, stream);
    prep_kernel<<<1, 512, 0, stream>>>(condraw, input, wsb);
    repack_kernel<<<2048, 256, 0, stream>>>(W0, W1, W2, wsb);
    lstm_persistent<<<NBLK, NTH, 0, stream>>>(input, b0, b1, b2, Wd, bd,
                                              gamma, beta, out, wsb);
}